// Round 1
// baseline (343.712 us; speedup 1.0000x reference)
//
#include <hip/hip_runtime.h>

// RIIDModelLSTM: 2-layer LSTM (H=6) over T=512, B=8192, fused FC(6->32->1) head.
// Mapping: 8 lanes per sequence; lane k owns hidden unit k (lanes 6,7 have
// zeroed weights -> h stays 0, identical code path, no divergence).
// Cross-lane: ds_swizzle broadcast of h0/h1 within 8-lane groups.
// FC head: 4 rows/lane across 8 lanes + xor-swizzle reduction, deferred by
// one timestep to stay off the recurrent critical path.

static constexpr float L2E = 1.44269504088896340736f;

template <int IMM>
__device__ __forceinline__ float swzf(float v) {
    return __int_as_float(__builtin_amdgcn_ds_swizzle(__float_as_int(v), IMM));
}

// broadcast lane (group_base + J) to all 8 lanes of the group (BitMode: and=0x18, or=J)
template <int J>
__device__ __forceinline__ float bcast8(float v) {
    return swzf<(J << 5) | 0x18>(v);
}

__device__ __forceinline__ float fast_sigmoid(float x) {
    float e = __builtin_amdgcn_exp2f(-L2E * x);
    return __builtin_amdgcn_rcpf(1.0f + e);
}

__device__ __forceinline__ float fast_tanh(float x) {
    // tanh(x) = 1 - 2/(1 + exp2(2*log2e*x)); saturates cleanly at +-1 (inf/0 in exp2)
    float e = __builtin_amdgcn_exp2f((2.0f * L2E) * x);
    return 1.0f - 2.0f * __builtin_amdgcn_rcpf(1.0f + e);
}

extern "C" __global__ void __launch_bounds__(256, 1)
lstm_fused_kernel(const float* __restrict__ x,
                  const float* __restrict__ wih0, const float* __restrict__ whh0,
                  const float* __restrict__ bih0, const float* __restrict__ bhh0,
                  const float* __restrict__ wih1, const float* __restrict__ whh1,
                  const float* __restrict__ bih1, const float* __restrict__ bhh1,
                  const float* __restrict__ fc1w_g, const float* __restrict__ fc1b_g,
                  const float* __restrict__ fc2w_g, const float* __restrict__ fc2b_g,
                  float* __restrict__ out, int nbatch)
{
    const int tid = blockIdx.x * blockDim.x + threadIdx.x;
    const int g   = tid & 7;        // lane within 8-lane group = hidden unit index
    const int bat = tid >> 3;       // sequence index
    if (bat >= nbatch) return;

    const float km = (g < 6) ? 1.0f : 0.0f;   // zero-mask for padding lanes 6,7
    const int   k  = (g < 6) ? g : 0;         // safe row index for padding lanes

    // ---- per-lane weights in VGPRs (all loops fully unrolled -> static indexing)
    float wi0[4][6], wh0[4][6], wi1[4][6], wh1[4][6];
    float bb0[4], bb1[4];
    float f1w[4][6], f1b[4], f2w[4];

#pragma unroll
    for (int m = 0; m < 4; ++m) {
        const int row = m * 6 + k;           // PyTorch gate order i,f,g,o
#pragma unroll
        for (int j = 0; j < 6; ++j) {
            wi0[m][j] = wih0[row * 6 + j] * km;
            wh0[m][j] = whh0[row * 6 + j] * km;
            wi1[m][j] = wih1[row * 6 + j] * km;
            wh1[m][j] = whh1[row * 6 + j] * km;
        }
        bb0[m] = (bih0[row] + bhh0[row]) * km;
        bb1[m] = (bih1[row] + bhh1[row]) * km;
        const int fr = g * 4 + m;            // fc1 rows 4g..4g+3 (all 8 lanes real)
#pragma unroll
        for (int j = 0; j < 6; ++j) f1w[m][j] = fc1w_g[fr * 6 + j];
        f1b[m] = fc1b_g[fr];
        f2w[m] = fc2w_g[fr];
    }
    const float f2b = fc2b_g[0];

    // ---- recurrent state
    float h0b[6], h1b[6];
#pragma unroll
    for (int j = 0; j < 6; ++j) { h0b[j] = 0.0f; h1b[j] = 0.0f; }
    float c0 = 0.0f, c1 = 0.0f;

    const float* xp = x + (size_t)bat * (512 * 6);
    float*       op = out + (size_t)bat * 512;

    // prefetch x[t=0] (6 floats, 8B-aligned: byte offset = bat*12288 + t*24)
    float xc[6];
    {
        float2 a = *(const float2*)(xp + 0);
        float2 b = *(const float2*)(xp + 2);
        float2 c = *(const float2*)(xp + 4);
        xc[0] = a.x; xc[1] = a.y; xc[2] = b.x; xc[3] = b.y; xc[4] = c.x; xc[5] = c.y;
    }

    for (int t = 0; t < 512; ++t) {
        // ---- prefetch x[t+1] (t=511 reloads t=511; harmless)
        const float* xnp = xp + (t + (t < 511)) * 6;
        float2 na = *(const float2*)(xnp + 0);
        float2 nb = *(const float2*)(xnp + 2);
        float2 nc = *(const float2*)(xnp + 4);

        // ---- deferred FC head on h1(t-1): off the recurrent critical path
        {
            float acc = 0.0f;
#pragma unroll
            for (int m = 0; m < 4; ++m) {
                float r = f1b[m];
#pragma unroll
                for (int j = 0; j < 6; ++j) r += f1w[m][j] * h1b[j];
                acc += f2w[m] * fmaxf(r, 0.0f);
            }
            acc += swzf<0x041F>(acc);   // xor 1
            acc += swzf<0x081F>(acc);   // xor 2
            acc += swzf<0x101F>(acc);   // xor 4
            float y = fmaxf(acc + f2b, 0.0f);
            if (t > 0 && g == 0) op[t - 1] = y;
        }

        // ---- cell-1 recurrent partial (depends only on h1(t-1)): hoisted
        float a1[4];
#pragma unroll
        for (int m = 0; m < 4; ++m) {
            float a = bb1[m];
#pragma unroll
            for (int j = 0; j < 6; ++j) a += wh1[m][j] * h1b[j];
            a1[m] = a;
        }

        // ---- cell 0: gates for hidden unit k
        float g0v[4];
#pragma unroll
        for (int m = 0; m < 4; ++m) {
            float a = bb0[m];
#pragma unroll
            for (int j = 0; j < 6; ++j) a += wi0[m][j] * xc[j];
#pragma unroll
            for (int j = 0; j < 6; ++j) a += wh0[m][j] * h0b[j];
            g0v[m] = a;
        }
        float i0 = fast_sigmoid(g0v[0]);
        float f0 = fast_sigmoid(g0v[1]);
        float t0 = fast_tanh(g0v[2]);
        float o0 = fast_sigmoid(g0v[3]);
        c0 = f0 * c0 + i0 * t0;
        float h0 = o0 * fast_tanh(c0);

        // broadcast h0 within the 8-lane group (sources: lanes 0..5)
        h0b[0] = bcast8<0>(h0);
        h0b[1] = bcast8<1>(h0);
        h0b[2] = bcast8<2>(h0);
        h0b[3] = bcast8<3>(h0);
        h0b[4] = bcast8<4>(h0);
        h0b[5] = bcast8<5>(h0);

        // ---- cell 1
        float g1v[4];
#pragma unroll
        for (int m = 0; m < 4; ++m) {
            float a = a1[m];
#pragma unroll
            for (int j = 0; j < 6; ++j) a += wi1[m][j] * h0b[j];
            g1v[m] = a;
        }
        float i1 = fast_sigmoid(g1v[0]);
        float f1 = fast_sigmoid(g1v[1]);
        float t1 = fast_tanh(g1v[2]);
        float o1 = fast_sigmoid(g1v[3]);
        c1 = f1 * c1 + i1 * t1;
        float h1 = o1 * fast_tanh(c1);

        h1b[0] = bcast8<0>(h1);
        h1b[1] = bcast8<1>(h1);
        h1b[2] = bcast8<2>(h1);
        h1b[3] = bcast8<3>(h1);
        h1b[4] = bcast8<4>(h1);
        h1b[5] = bcast8<5>(h1);

        // ---- rotate prefetched x
        xc[0] = na.x; xc[1] = na.y; xc[2] = nb.x; xc[3] = nb.y; xc[4] = nc.x; xc[5] = nc.y;
    }

    // ---- final FC head for t = 511
    {
        float acc = 0.0f;
#pragma unroll
        for (int m = 0; m < 4; ++m) {
            float r = f1b[m];
#pragma unroll
            for (int j = 0; j < 6; ++j) r += f1w[m][j] * h1b[j];
            acc += f2w[m] * fmaxf(r, 0.0f);
        }
        acc += swzf<0x041F>(acc);
        acc += swzf<0x081F>(acc);
        acc += swzf<0x101F>(acc);
        float y = fmaxf(acc + f2b, 0.0f);
        if (g == 0) op[511] = y;
    }
}

extern "C" void kernel_launch(void* const* d_in, const int* in_sizes, int n_in,
                              void* d_out, int out_size, void* d_ws, size_t ws_size,
                              hipStream_t stream) {
    const float* x     = (const float*)d_in[0];
    const float* wih0  = (const float*)d_in[1];
    const float* whh0  = (const float*)d_in[2];
    const float* bih0  = (const float*)d_in[3];
    const float* bhh0  = (const float*)d_in[4];
    const float* wih1  = (const float*)d_in[5];
    const float* whh1  = (const float*)d_in[6];
    const float* bih1  = (const float*)d_in[7];
    const float* bhh1  = (const float*)d_in[8];
    const float* fc1w  = (const float*)d_in[9];
    const float* fc1b  = (const float*)d_in[10];
    const float* fc2w  = (const float*)d_in[11];
    const float* fc2b  = (const float*)d_in[12];
    float* out = (float*)d_out;

    const int nbatch = in_sizes[0] / (512 * 6);   // 8192
    const int threads = nbatch * 8;               // 8 lanes per sequence
    const int block = 256;
    const int grid = (threads + block - 1) / block;

    hipLaunchKernelGGL(lstm_fused_kernel, dim3(grid), dim3(block), 0, stream,
                       x, wih0, whh0, bih0, bhh0, wih1, whh1, bih1, bhh1,
                       fc1w, fc1b, fc2w, fc2b, out, nbatch);
}

// Round 2
// 306.440 us; speedup vs baseline: 1.1216x; 1.1216x over previous
//
#include <hip/hip_runtime.h>

// RIIDModelLSTM: 2-layer LSTM (H=6) over T=512, B=8192, fused FC(6->32->1) head.
//
// Mapping (v2): 16 lanes per sequence, 2 waves/SIMD device-wide.
//   lane sub = tid&15; half = sub>>3; k = sub&7 (unit; k=6,7 padded with zero wts)
//   half=0 lane computes gates (i,f) of unit k; half=1 computes (g,o).
//   Gates packed as float2 -> v_pk_fma_f32. One xor-8 swizzle pair swaps
//   activations so BOTH lanes hold (i,f,g,o) and redundantly compute c,h in
//   the same instruction slots (no divergence, no extra latency).
//   sigma/tanh unified: f(x) = 1 - B*rcp(1 + exp2(S*x)), S folded into weights.
// Cross-lane: ds_swizzle only. FC head: 2 rows/lane x 16 lanes, xor-reduce,
// deferred one timestep off the recurrent critical path.

typedef float v2f __attribute__((ext_vector_type(2)));

static constexpr float L2E = 1.44269504088896340736f;

template <int IMM>
__device__ __forceinline__ float swzf(float v) {
    return __int_as_float(__builtin_amdgcn_ds_swizzle(__float_as_int(v), IMM));
}

// broadcast lane ((lane&0x10)|J) of the 32-lane group -> unit J of own sequence
template <int J>
__device__ __forceinline__ float bcast16(float v) {
    return swzf<(J << 5) | 0x10>(v);
}

__device__ __forceinline__ float tanh_fast(float x) {
    float e = __builtin_amdgcn_exp2f((2.0f * L2E) * x);
    return 1.0f - 2.0f * __builtin_amdgcn_rcpf(1.0f + e);
}

extern "C" __global__ void __launch_bounds__(256, 2)
lstm_fused16(const float* __restrict__ x,
             const float* __restrict__ wih0, const float* __restrict__ whh0,
             const float* __restrict__ bih0, const float* __restrict__ bhh0,
             const float* __restrict__ wih1, const float* __restrict__ whh1,
             const float* __restrict__ bih1, const float* __restrict__ bhh1,
             const float* __restrict__ fc1w_g, const float* __restrict__ fc1b_g,
             const float* __restrict__ fc2w_g, const float* __restrict__ fc2b_g,
             float* __restrict__ out, int nbatch)
{
    const int tid  = blockIdx.x * blockDim.x + threadIdx.x;
    const int sub  = tid & 15;       // lane within sequence group
    const int seq  = tid >> 4;       // sequence index
    if (seq >= nbatch) return;

    const int   half = sub >> 3;     // 0: gates (i,f); 1: gates (g,o)
    const int   k    = sub & 7;      // hidden unit
    const float km   = (k < 6) ? 1.0f : 0.0f;   // pad lanes 6,7 -> zero weights
    const int   kk   = (k < 6) ? k : 0;

    // activation params: f(x)=1-B*rcp(1+exp2(S*x)); S folded into weights.
    // .x gate: sigmoid (half=0) or tanh (half=1); .y gate: always sigmoid.
    const float Bx  = half ? 2.0f : 1.0f;
    const float sxw = km * (half ? (2.0f * L2E) : L2E);
    const float syw = km * L2E;

    // ---- per-lane weights (gate rows 2*half, 2*half+1 of unit kk), pre-scaled
    const int r0 = (2 * half    ) * 6 + kk;
    const int r1 = (2 * half + 1) * 6 + kk;

    v2f wi0[6], wh0[6], wi1[6], wh1[6];
#pragma unroll
    for (int j = 0; j < 6; ++j) {
        wi0[j] = (v2f){ wih0[r0 * 6 + j] * sxw, wih0[r1 * 6 + j] * syw };
        wh0[j] = (v2f){ whh0[r0 * 6 + j] * sxw, whh0[r1 * 6 + j] * syw };
        wi1[j] = (v2f){ wih1[r0 * 6 + j] * sxw, wih1[r1 * 6 + j] * syw };
        wh1[j] = (v2f){ whh1[r0 * 6 + j] * sxw, whh1[r1 * 6 + j] * syw };
    }
    const v2f bb0 = (v2f){ (bih0[r0] + bhh0[r0]) * sxw, (bih0[r1] + bhh0[r1]) * syw };
    const v2f bb1 = (v2f){ (bih1[r0] + bhh1[r0]) * sxw, (bih1[r1] + bhh1[r1]) * syw };

    // ---- FC head: rows 2*sub, 2*sub+1 (all 32 rows covered by 16 lanes)
    v2f f1w[6];
    const int fr0 = 2 * sub, fr1 = 2 * sub + 1;
#pragma unroll
    for (int j = 0; j < 6; ++j)
        f1w[j] = (v2f){ fc1w_g[fr0 * 6 + j], fc1w_g[fr1 * 6 + j] };
    const v2f  f1b = (v2f){ fc1b_g[fr0], fc1b_g[fr1] };
    const v2f  f2w = (v2f){ fc2w_g[fr0], fc2w_g[fr1] };
    const float f2b = fc2b_g[0];

    // ---- recurrent state
    float h0b[6], h1b[6];
#pragma unroll
    for (int j = 0; j < 6; ++j) { h0b[j] = 0.0f; h1b[j] = 0.0f; }
    float c0 = 0.0f, c1 = 0.0f;

    const float* xp = x + (size_t)seq * (512 * 6);
    float*       op = out + (size_t)seq * 512;

    // prefetch x[0] (6 floats, 8B-aligned)
    float xc[6];
    {
        float2 a = *(const float2*)(xp + 0);
        float2 b = *(const float2*)(xp + 2);
        float2 c = *(const float2*)(xp + 4);
        xc[0] = a.x; xc[1] = a.y; xc[2] = b.x; xc[3] = b.y; xc[4] = c.x; xc[5] = c.y;
    }

    for (int t = 0; t < 512; ++t) {
        // ---- prefetch x[t+1]
        const float* xnp = xp + (t + (t < 511)) * 6;
        float2 na = *(const float2*)(xnp + 0);
        float2 nb = *(const float2*)(xnp + 2);
        float2 nc = *(const float2*)(xnp + 4);

        // ---- deferred FC head on h1(t-1)
        {
            v2f ra = f1b, rb = (v2f){0.0f, 0.0f};
            ra += f1w[0] * h1b[0];  rb += f1w[1] * h1b[1];
            ra += f1w[2] * h1b[2];  rb += f1w[3] * h1b[3];
            ra += f1w[4] * h1b[4];  rb += f1w[5] * h1b[5];
            v2f r = ra + rb;
            float acc = f2w.x * fmaxf(r.x, 0.0f) + f2w.y * fmaxf(r.y, 0.0f);
            acc += swzf<0x041F>(acc);   // xor 1
            acc += swzf<0x081F>(acc);   // xor 2
            acc += swzf<0x101F>(acc);   // xor 4
            acc += swzf<0x201F>(acc);   // xor 8 -> 16-lane sum
            if (t > 0 && sub == 0) op[t - 1] = fmaxf(acc + f2b, 0.0f);
        }

        // ---- cell1 recurrent partial (depends only on h1(t-1)): hoisted
        v2f a1a = bb1, a1b = (v2f){0.0f, 0.0f};
        a1a += wh1[0] * h1b[0];  a1b += wh1[1] * h1b[1];
        a1a += wh1[2] * h1b[2];  a1b += wh1[3] * h1b[3];
        a1a += wh1[4] * h1b[4];  a1b += wh1[5] * h1b[5];

        // ---- cell 0 gates (pre-scaled preactivations)
        v2f ga = bb0, gb = (v2f){0.0f, 0.0f};
        ga += wi0[0] * xc[0];   gb += wi0[1] * xc[1];
        ga += wi0[2] * xc[2];   gb += wi0[3] * xc[3];
        ga += wi0[4] * xc[4];   gb += wi0[5] * xc[5];
        ga += wh0[0] * h0b[0];  gb += wh0[1] * h0b[1];
        ga += wh0[2] * h0b[2];  gb += wh0[3] * h0b[3];
        ga += wh0[4] * h0b[4];  gb += wh0[5] * h0b[5];
        v2f gv = ga + gb;

        float ax = 1.0f - Bx * __builtin_amdgcn_rcpf(1.0f + __builtin_amdgcn_exp2f(gv.x));
        float ay = 1.0f -      __builtin_amdgcn_rcpf(1.0f + __builtin_amdgcn_exp2f(gv.y));
        // swap with partner lane (xor 8): both halves now hold all 4 gates
        float sx = swzf<0x201F>(ax);
        float sy = swzf<0x201F>(ay);
        float fg = half ? sy : ay;      // forget gate
        float og = half ? ay : sy;      // output gate
        c0 = fg * c0 + ax * sx;         // i*g == ax*sx on both halves
        float h0 = og * tanh_fast(c0);

        h0b[0] = bcast16<0>(h0);
        h0b[1] = bcast16<1>(h0);
        h0b[2] = bcast16<2>(h0);
        h0b[3] = bcast16<3>(h0);
        h0b[4] = bcast16<4>(h0);
        h0b[5] = bcast16<5>(h0);

        // ---- cell 1 gates
        a1a += wi1[0] * h0b[0];  a1b += wi1[1] * h0b[1];
        a1a += wi1[2] * h0b[2];  a1b += wi1[3] * h0b[3];
        a1a += wi1[4] * h0b[4];  a1b += wi1[5] * h0b[5];
        v2f g1 = a1a + a1b;

        float ax1 = 1.0f - Bx * __builtin_amdgcn_rcpf(1.0f + __builtin_amdgcn_exp2f(g1.x));
        float ay1 = 1.0f -      __builtin_amdgcn_rcpf(1.0f + __builtin_amdgcn_exp2f(g1.y));
        float sx1 = swzf<0x201F>(ax1);
        float sy1 = swzf<0x201F>(ay1);
        float fg1 = half ? sy1 : ay1;
        float og1 = half ? ay1 : sy1;
        c1 = fg1 * c1 + ax1 * sx1;
        float h1 = og1 * tanh_fast(c1);

        h1b[0] = bcast16<0>(h1);
        h1b[1] = bcast16<1>(h1);
        h1b[2] = bcast16<2>(h1);
        h1b[3] = bcast16<3>(h1);
        h1b[4] = bcast16<4>(h1);
        h1b[5] = bcast16<5>(h1);

        // ---- rotate prefetched x
        xc[0] = na.x; xc[1] = na.y; xc[2] = nb.x; xc[3] = nb.y; xc[4] = nc.x; xc[5] = nc.y;
    }

    // ---- final FC head for t = 511
    {
        v2f ra = f1b, rb = (v2f){0.0f, 0.0f};
        ra += f1w[0] * h1b[0];  rb += f1w[1] * h1b[1];
        ra += f1w[2] * h1b[2];  rb += f1w[3] * h1b[3];
        ra += f1w[4] * h1b[4];  rb += f1w[5] * h1b[5];
        v2f r = ra + rb;
        float acc = f2w.x * fmaxf(r.x, 0.0f) + f2w.y * fmaxf(r.y, 0.0f);
        acc += swzf<0x041F>(acc);
        acc += swzf<0x081F>(acc);
        acc += swzf<0x101F>(acc);
        acc += swzf<0x201F>(acc);
        if (sub == 0) op[511] = fmaxf(acc + f2b, 0.0f);
    }
}

extern "C" void kernel_launch(void* const* d_in, const int* in_sizes, int n_in,
                              void* d_out, int out_size, void* d_ws, size_t ws_size,
                              hipStream_t stream) {
    const float* x     = (const float*)d_in[0];
    const float* wih0  = (const float*)d_in[1];
    const float* whh0  = (const float*)d_in[2];
    const float* bih0  = (const float*)d_in[3];
    const float* bhh0  = (const float*)d_in[4];
    const float* wih1  = (const float*)d_in[5];
    const float* whh1  = (const float*)d_in[6];
    const float* bih1  = (const float*)d_in[7];
    const float* bhh1  = (const float*)d_in[8];
    const float* fc1w  = (const float*)d_in[9];
    const float* fc1b  = (const float*)d_in[10];
    const float* fc2w  = (const float*)d_in[11];
    const float* fc2b  = (const float*)d_in[12];
    float* out = (float*)d_out;

    const int nbatch  = in_sizes[0] / (512 * 6);   // 8192
    const int threads = nbatch * 16;               // 16 lanes per sequence
    const int block   = 256;
    const int grid    = (threads + block - 1) / block;

    hipLaunchKernelGGL(lstm_fused16, dim3(grid), dim3(block), 0, stream,
                       x, wih0, whh0, bih0, bhh0, wih1, whh1, bih1, bhh1,
                       fc1w, fc1b, fc2w, fc2b, out, nbatch);
}